// Round 10
// baseline (935.136 us; speedup 1.0000x reference)
//
#include <hip/hip_runtime.h>
#include <hip/hip_bf16.h>

#define PX 9216      // 96*96
#define LL 9216
#define HALF_L 4608
#define CCH 4        // emitted steps per chunk
#define NCHUNK 2304  // 9216/4
#define WARM 48      // burn-in steps (12 chunks of pre-pad)
#define PADC 12      // WARM/CCH
#define NCP  2316    // NCHUNK + PADC
#define RS   74112   // 32*NCP (row stride per s, in elements)
#define NITER 50

// ws offsets (floats)
#define OFF_WC   0        // 32 scaled GRU consts
#define OFF_FLAG 32
#define OFF_HL   40       // 128
#define OFF_W1   192      // 144
#define OFF_B1   336      // 16
#define OFF_W2   384      // 4608
#define OFF_B2   4992     // 32
#define OFF_W3   5024     // 864
#define OFF_B3   5888     // 3
#define OFF_KX   5896     // 9
#define OFF_KY   5908     // 9
#define OFF_GA4  8192     // 296448 float4 (+16) = 1185856 floats
#define OFF_GB4  1194048
#define OFF_GA2  2379904  // 296448 float2 (+32) = 592960 floats
#define OFF_GB2  2972864
#define OFF_Y2   3565824  // end 4158784 floats = 16.6 MB

static __device__ __forceinline__ float ldv(const void* p, long i, bool isb) {
    return isb ? __bfloat162float(((const __hip_bfloat16*)p)[i])
               : ((const float*)p)[i];
}

__global__ __launch_bounds__(256) void k_prep(
    float* __restrict__ ws, const void* img,
    const void* w1, const void* b1, const void* w2, const void* b2,
    const void* w3, const void* b3, const void* kx, const void* ky,
    const void* wih, const void* whh, const void* bih, const void* bhh)
{
    __shared__ float s_isb;
    int t = threadIdx.x;
    if (t == 0) {
        const unsigned short* u16 = (const unsigned short*)img;
        int cnt = 0;
        for (int k = 0; k < 256; ++k) {
            unsigned short u = u16[k];
            int e = (u >> 7) & 0xFF;
            bool ok = (u == 0) || (((u & 0x8000) == 0) && e >= 0x20 && e <= 0x7E);
            cnt += ok ? 1 : 0;
        }
        s_isb = (cnt >= 224) ? 1.f : 0.f;
        ws[OFF_FLAG] = s_isb;
    }
    __syncthreads();
    bool isb = s_isb > 0.5f;

    for (int i = t; i < 144; i += 256) { int co = i/9, tap = i%9; ws[OFF_W1 + tap*16 + co] = ldv(w1,i,isb); }
    for (int i = t; i < 16; i += 256) ws[OFF_B1+i] = ldv(b1,i,isb);
    for (int i = t; i < 4608; i += 256) { int co = i/144, r = i%144, ci = r/9, tap = r%9;
        ws[OFF_W2 + (ci*9+tap)*32 + co] = ldv(w2,i,isb); }
    for (int i = t; i < 32; i += 256) ws[OFF_B2+i] = ldv(b2,i,isb);
    for (int i = t; i < 864; i += 256) { int o = i/288, r = i%288, ci = r/9, tap = r%9;
        ws[OFF_W3 + (ci*9+tap)*3 + o] = ldv(w3,i,isb); }
    for (int i = t; i < 3; i += 256) ws[OFF_B3+i] = ldv(b3,i,isb);
    for (int i = t; i < 9; i += 256) { ws[OFF_KX+i] = ldv(kx,i,isb); ws[OFF_KY+i] = ldv(ky,i,isb); }
    for (int i = t; i < 128; i += 256) ws[OFF_HL+i] = 0.f;
    if (t == 0) {
        const float C1 = 1.4426950408889634f;
        for (int g = 0; g < 4; ++g) {   // r,z gates: sigmoid = rcp(1+exp2(-x*log2e))
            ws[OFF_WC + g*2+0]     = -C1*ldv(wih, g*2+0, isb);
            ws[OFF_WC + g*2+1]     = -C1*ldv(wih, g*2+1, isb);
            ws[OFF_WC + 8 + g*2+0] = -C1*ldv(whh, g*2+0, isb);
            ws[OFF_WC + 8 + g*2+1] = -C1*ldv(whh, g*2+1, isb);
            ws[OFF_WC + 16 + g]    = -C1*(ldv(bih,g,isb)+ldv(bhh,g,isb));
        }
        for (int j = 0; j < 2; ++j) {   // n gate: tanh(t)=1-2/(1+2^(2t*log2e))
            int g = 4+j;
            ws[OFF_WC + 20 + j*2+0] = 2.f*C1*ldv(wih, g*2+0, isb);
            ws[OFF_WC + 20 + j*2+1] = 2.f*C1*ldv(wih, g*2+1, isb);
            ws[OFF_WC + 24 + j*2+0] = 2.f*C1*ldv(whh, g*2+0, isb);
            ws[OFF_WC + 24 + j*2+1] = 2.f*C1*ldv(whh, g*2+1, isb);
            ws[OFF_WC + 28 + j]     = 2.f*C1*ldv(bih, g, isb);
            ws[OFF_WC + 30 + j]     = 2.f*C1*ldv(bhh, g, isb);
        }
    }
}

// fused preamble: gray -> sobel + conv1 -> conv2 -> conv3 -> argmax -> pack gi
// 32x8 output tile per block; all intermediates in LDS.
__global__ __launch_bounds__(256) void k_all(float* __restrict__ ws,
                                             const void* __restrict__ img)
{
    __shared__ float gt[532];        // gray: 14 rows x 38 cols
    __shared__ float c1[6912];       // 16 ch x 12 rows x 36 cols
    __shared__ float c2[10880];      // 32 ch x 10 rows x 34 cols
    bool isb = ws[OFF_FLAG] > 0.5f;
    int bb = blockIdx.x / 36, tI = blockIdx.x % 36;
    int ty0 = (tI / 3) * 8, tx0 = (tI % 3) * 32;
    int t = threadIdx.x;
    long ibase = (long)bb*3*PX;

    // stage A: gray halo 38x14 (origin -3,-3)
    for (int i = t; i < 532; i += 256) {
        int yy = i / 38, xx = i - yy*38;
        int gy = ty0 + yy - 3, gx = tx0 + xx - 3;
        float v = 0.f;
        if (gy >= 0 && gy < 96 && gx >= 0 && gx < 96) {
            long pp = gy*96 + gx;
            float r  = ldv(img, ibase + pp, isb);
            float g  = ldv(img, ibase + PX + pp, isb);
            float bl = ldv(img, ibase + 2*PX + pp, isb);
            v = fmaf(0.2989f, r, fmaf(0.587f, g, 0.114f*bl));
        }
        gt[i] = v;
    }
    __syncthreads();

    // sobel G for the 32x8 interior (gray local +3)
    int y3 = t >> 5, x3 = t & 31;
    float sx = 0.f, sy = 0.f;
    #pragma unroll
    for (int dy = 0; dy < 3; ++dy)
    #pragma unroll
    for (int dx = 0; dx < 3; ++dx) {
        float v = gt[(y3+2+dy)*38 + (x3+2+dx)];
        sx = fmaf(v, ws[OFF_KX + dy*3+dx], sx);
        sy = fmaf(v, ws[OFF_KY + dy*3+dx], sy);
    }
    float G = sqrtf(fmaf(sx, sx, sy*sy));

    // stage B: conv1 -> C1 at 36x12 (origin -2,-2); gray local = pos + (1,1) - 1 + tap
    #pragma unroll
    for (int pass = 0; pass < 2; ++pass) {
        int q = t + pass*256;
        if (q < 432) {
            int y1 = q / 36, x1 = q - y1*36;
            float acc[16];
            #pragma unroll
            for (int co = 0; co < 16; ++co) acc[co] = 0.f;
            #pragma unroll
            for (int dy = 0; dy < 3; ++dy)
            #pragma unroll
            for (int dx = 0; dx < 3; ++dx) {
                float v = gt[(y1+dy)*38 + x1+dx];
                const float* w = ws + OFF_W1 + (dy*3+dx)*16;
                #pragma unroll
                for (int co = 0; co < 16; ++co) acc[co] = fmaf(v, w[co], acc[co]);
            }
            #pragma unroll
            for (int co = 0; co < 16; ++co)
                c1[co*432 + y1*36 + x1] = fmaxf(acc[co] + ws[OFF_B1+co], 0.f);
        }
    }
    __syncthreads();

    // stage C: conv2 -> C2 at 34x10 (origin -1,-1); C1 local = pos + tap
    #pragma unroll
    for (int pass = 0; pass < 2; ++pass) {
        int q = t + pass*256;
        if (q < 340) {
            int y2 = q / 34, x2 = q - y2*34;
            float acc[32];
            #pragma unroll
            for (int co = 0; co < 32; ++co) acc[co] = 0.f;
            for (int ci = 0; ci < 16; ++ci) {
                #pragma unroll
                for (int dy = 0; dy < 3; ++dy)
                #pragma unroll
                for (int dx = 0; dx < 3; ++dx) {
                    float v = c1[ci*432 + (y2+dy)*36 + (x2+dx)];
                    const float* w = ws + OFF_W2 + (ci*9 + dy*3 + dx)*32;
                    #pragma unroll
                    for (int co = 0; co < 32; ++co) acc[co] = fmaf(v, w[co], acc[co]);
                }
            }
            #pragma unroll
            for (int co = 0; co < 32; ++co)
                c2[co*340 + y2*34 + x2] = fmaxf(acc[co] + ws[OFF_B2+co], 0.f);
        }
    }
    __syncthreads();

    // stage D: conv3 + argmax at 32x8 (C2 local = pos + tap)
    float a0 = 0.f, a1 = 0.f, a2 = 0.f;
    for (int ci = 0; ci < 32; ++ci) {
        #pragma unroll
        for (int dy = 0; dy < 3; ++dy)
        #pragma unroll
        for (int dx = 0; dx < 3; ++dx) {
            float v = c2[ci*340 + (y3+dy)*34 + (x3+dx)];
            const float* w = ws + OFF_W3 + (ci*9 + dy*3 + dx)*3;
            a0 = fmaf(v, w[0], a0);
            a1 = fmaf(v, w[1], a1);
            a2 = fmaf(v, w[2], a2);
        }
    }
    a0 += ws[OFF_B3+0]; a1 += ws[OFF_B3+1]; a2 += ws[OFF_B3+2];
    int mi = 0; float best = a0;
    if (a1 > best) { best = a1; mi = 1; }
    if (a2 > best) { mi = 2; }
    float m = (float)mi;

    // stage E: pack markers (l < 4608) and G (l >= 4608) as gate inputs
    float mn = __shfl_down(m, 1, 64);
    float Gn = __shfl_down(G, 1, 64);
    if ((t & 1) == 0) {
        int p = (ty0+y3)*96 + tx0 + x3;
        const float* kk = ws + OFF_WC;
        #pragma unroll
        for (int which = 0; which < 2; ++which) {
            float v0 = which ? G  : m;
            float v1 = which ? Gn : mn;
            int l = (which ? HALF_L : 0) + (p >> 1);
            int cc = (l >> 2) + PADC, s = l & 3;
            long idx = (long)(s*32 + bb)*NCP + cc;
            float4 g4;
            g4.x = fmaf(kk[0], v0, fmaf(kk[1], v1, kk[16]));
            g4.y = fmaf(kk[2], v0, fmaf(kk[3], v1, kk[17]));
            g4.z = fmaf(kk[4], v0, fmaf(kk[5], v1, kk[18]));
            g4.w = fmaf(kk[6], v0, fmaf(kk[7], v1, kk[19]));
            float2 g2;
            g2.x = fmaf(kk[20], v0, fmaf(kk[21], v1, kk[28]));
            g2.y = fmaf(kk[22], v0, fmaf(kk[23], v1, kk[29]));
            ((float4*)(ws + OFF_GA4))[idx] = g4;
            ((float2*)(ws + OFF_GA2))[idx] = g2;
        }
    }
}

__global__ __launch_bounds__(64) void k_gru(const float* __restrict__ ws,
                                            const float4* __restrict__ S4,
                                            const float2* __restrict__ S2,
                                            float4* __restrict__ D4,
                                            float2* __restrict__ D2,
                                            float2* __restrict__ Y2,
                                            const float* __restrict__ hlin,
                                            float* __restrict__ hlout,
                                            int last)
{
    int i = blockIdx.x*64 + threadIdx.x;    // 73728 threads exactly
    int b = i / NCHUNK, c = i - b*NCHUNK;
    float kk[32];
    #pragma unroll
    for (int j = 0; j < 32; ++j) kk[j] = ws[OFF_WC + j];

    int jstar = WARM - c*CCH;               // trip-aligned exact-carry reset
    float hl0 = hlin[2*b], hl1 = hlin[2*b+1];
    float h0 = 0.f, h1 = 0.f;
    long B0 = (long)b*NCP + c;

    auto STEP = [&](const float4& g4, float gn0, float gn1) {
        float ar0 = fmaf(kk[8],  h0, fmaf(kk[9],  h1, g4.x));
        float ar1 = fmaf(kk[10], h0, fmaf(kk[11], h1, g4.y));
        float az0 = fmaf(kk[12], h0, fmaf(kk[13], h1, g4.z));
        float az1 = fmaf(kk[14], h0, fmaf(kk[15], h1, g4.w));
        float er0 = __builtin_amdgcn_exp2f(ar0);
        float er1 = __builtin_amdgcn_exp2f(ar1);
        float ez0 = __builtin_amdgcn_exp2f(az0);
        float ez1 = __builtin_amdgcn_exp2f(az1);
        float tr0 = 1.f+er0, tr1 = 1.f+er1, tz0 = 1.f+ez0, tz1 = 1.f+ez1;
        float t1 = tr0*tr1, t2 = tz0*tz1;
        float inv = __builtin_amdgcn_rcpf(t1*t2);   // 4-way paired reciprocal
        float i1 = inv*t2, i2 = inv*t1;
        float r0 = i1*tr1, r1 = i1*tr0;
        float z0 = i2*tz1, z1 = i2*tz0;
        float omz0 = z0*ez0, omz1 = z1*ez1;   // 1-sigmoid == sigmoid*e
        float zh0 = z0*h0, zh1 = z1*h1;
        float hn0 = fmaf(kk[24], h0, fmaf(kk[25], h1, kk[30]));
        float hn1 = fmaf(kk[26], h0, fmaf(kk[27], h1, kk[31]));
        float u0 = fmaf(r0, hn0, gn0);
        float u1 = fmaf(r1, hn1, gn1);
        float en0 = __builtin_amdgcn_exp2f(u0);
        float en1 = __builtin_amdgcn_exp2f(u1);
        float sn0 = 1.f+en0, sn1 = 1.f+en1;
        float iN = __builtin_amdgcn_rcpf(sn0*sn1);
        float m2 = -2.f*iN;
        float n0 = fmaf(m2, sn1, 1.f);
        float n1 = fmaf(m2, sn0, 1.f);
        h0 = fmaf(n0, omz0, zh0);
        h1 = fmaf(n1, omz1, zh1);
    };

    // preload column B0 (trip 0)
    float4 c40 = S4[B0], c41 = S4[B0+RS], c42 = S4[B0+2*(long)RS], c43 = S4[B0+3*(long)RS];
    float2 c2a = S2[B0], c2b = S2[B0+RS], c2c = S2[B0+2*(long)RS], c2d = S2[B0+3*(long)RS];

    for (int T = 0; T < 13; ++T) {          // 13 trips x 4 = 52 steps
        long bn = B0 + T + 1;               // one column per trip
        float4 p0 = S4[bn], p1 = S4[bn+RS], p2 = S4[bn+2*(long)RS], p3 = S4[bn+3*(long)RS];
        float2 q0 = S2[bn], q1 = S2[bn+RS], q2 = S2[bn+2*(long)RS], q3 = S2[bn+3*(long)RS];
        if (4*T == jstar) { h0 = hl0; h1 = hl1; }
        STEP(c40, c2a.x, c2a.y); float a00 = h0, a01 = h1;
        STEP(c41, c2b.x, c2b.y); float a10 = h0, a11 = h1;
        STEP(c42, c2c.x, c2c.y); float a20 = h0, a21 = h1;
        STEP(c43, c2d.x, c2d.y); float a30 = h0, a31 = h1;
        if (T == 12) {                      // emit the chunk's CCH=4 steps
            float e00 = fmaxf(a00,0.f), e01 = fmaxf(a01,0.f);
            float e10 = fmaxf(a10,0.f), e11 = fmaxf(a11,0.f);
            float e20 = fmaxf(a20,0.f), e21 = fmaxf(a21,0.f);
            float e30 = fmaxf(a30,0.f), e31 = fmaxf(a31,0.f);
            long db = B0 + PADC;
            if (!last) {
                float ee[4][2] = {{e00,e01},{e10,e11},{e20,e21},{e30,e31}};
                #pragma unroll
                for (int k = 0; k < 4; ++k) {
                    float v0 = ee[k][0], v1 = ee[k][1];
                    float4 g4;
                    g4.x = fmaf(kk[0], v0, fmaf(kk[1], v1, kk[16]));
                    g4.y = fmaf(kk[2], v0, fmaf(kk[3], v1, kk[17]));
                    g4.z = fmaf(kk[4], v0, fmaf(kk[5], v1, kk[18]));
                    g4.w = fmaf(kk[6], v0, fmaf(kk[7], v1, kk[19]));
                    float2 g2;
                    g2.x = fmaf(kk[20], v0, fmaf(kk[21], v1, kk[28]));
                    g2.y = fmaf(kk[22], v0, fmaf(kk[23], v1, kk[29]));
                    D4[db + k*(long)RS] = g4;
                    D2[db + k*(long)RS] = g2;
                }
            } else {
                Y2[db + 0*(long)RS] = make_float2(e00, e01);
                Y2[db + 1*(long)RS] = make_float2(e10, e11);
                Y2[db + 2*(long)RS] = make_float2(e20, e21);
                Y2[db + 3*(long)RS] = make_float2(e30, e31);
            }
        }
        c40 = p0; c41 = p1; c42 = p2; c43 = p3;
        c2a = q0; c2b = q1; c2c = q2; c2d = q3;
    }
    if (c == NCHUNK-1) { hlout[2*b] = h0; hlout[2*b+1] = h1; }
}

__global__ __launch_bounds__(256) void k_out(const float* __restrict__ ws,
                                             const void* __restrict__ ow,
                                             const void* __restrict__ ob,
                                             void* __restrict__ out)
{
    bool isb = ws[OFF_FLAG] > 0.5f;
    int t = blockIdx.x*256 + threadIdx.x;
    int b = t / PX, p = t - b*PX;
    int cc = (p >> 2) + PADC, s = p & 3;
    float2 v = ((const float2*)(ws + OFF_Y2))[(long)(s*32 + b)*NCP + cc];
    #pragma unroll
    for (int o = 0; o < 3; ++o) {
        float w0 = ldv(ow, o*2,   isb);
        float w1 = ldv(ow, o*2+1, isb);
        float bi = ldv(ob, o,     isb);
        float r = fmaf(v.y, w1, fmaf(v.x, w0, bi));
        long idx = (long)(b*3 + o)*PX + p;
        if (isb) ((__hip_bfloat16*)out)[idx] = __float2bfloat16(r);
        else     ((float*)out)[idx] = r;
    }
}

extern "C" void kernel_launch(void* const* d_in, const int* in_sizes, int n_in,
                              void* d_out, int out_size, void* d_ws, size_t ws_size,
                              hipStream_t stream)
{
    (void)in_sizes; (void)n_in; (void)out_size; (void)ws_size;
    float* ws = (float*)d_ws;
    const void* img = d_in[0];
    const void* kx  = d_in[1];
    const void* ky  = d_in[2];
    const void* w1  = d_in[3];
    const void* b1  = d_in[4];
    const void* w2  = d_in[5];
    const void* b2  = d_in[6];
    const void* w3  = d_in[7];
    const void* b3  = d_in[8];
    const void* wih = d_in[9];
    const void* whh = d_in[10];
    const void* bih = d_in[11];
    const void* bhh = d_in[12];
    const void* owp = d_in[13];
    const void* obp = d_in[14];

    k_prep<<<1, 256, 0, stream>>>(ws, img, w1,b1,w2,b2,w3,b3,kx,ky,wih,whh,bih,bhh);
    k_all<<<1152, 256, 0, stream>>>(ws, img);

    float4* ga4 = (float4*)(ws + OFF_GA4);
    float4* gb4 = (float4*)(ws + OFF_GB4);
    float2* ga2 = (float2*)(ws + OFF_GA2);
    float2* gb2 = (float2*)(ws + OFF_GB2);
    float2* y2  = (float2*)(ws + OFF_Y2);
    float* hl = ws + OFF_HL;
    for (int it = 0; it < NITER; ++it) {
        const float4* s4 = (it & 1) ? (const float4*)gb4 : (const float4*)ga4;
        const float2* s2 = (it & 1) ? (const float2*)gb2 : (const float2*)ga2;
        float4* d4 = (it & 1) ? ga4 : gb4;
        float2* d2 = (it & 1) ? ga2 : gb2;
        k_gru<<<1152, 64, 0, stream>>>(ws, s4, s2, d4, d2, y2,
                                       hl + (it & 1)*64, hl + ((it + 1) & 1)*64,
                                       (it == NITER-1) ? 1 : 0);
    }
    k_out<<<1152, 256, 0, stream>>>(ws, owp, obp, (void*)d_out);
}